// Round 3
// baseline (16.527 us; speedup 1.0000x reference)
//
#include <hip/hip_runtime.h>
#include <math.h>

// Fused SPDS extractor, single dispatch:
//   for p in {2,4,8}: sliding p×p patches (stride p/2) -> per-patch mean,
//   std(ddof=1)+1e-6, and (p==2) channel-mean of sign(det)*|det|^0.7,
//   each plane bilinear-resized (align_corners=False) to 32x32.
//
// R2 changes:
//  * Uniform y-split loads: the 2 y-corner lanes of a pixel split the
//    (P+P/2)-row column union evenly (6 rows each for P=8, 3 for P=4),
//    reconstructing both patch sums via shfl_xor(2) partial-sum exchange.
//    -25% load instrs and bytes on the dominant scales, no divergence.
//    (Valid because yh==yl+1 always for these shapes: sy,sx never clamp.)
//  * XCD-aware block swizzle, grouped per image: each XCD gets 4 whole
//    images x all 3 scales (3.1MB, L2-resident) -> halo + cross-scale reuse.
//
// Thread map per scale: tid -> (b, oy, ox, corner); corner = tid&3 so the 4
// corners of one output pixel are lanes {4k..4k+3}; combined via shfl_xor(1/2).

__device__ __forceinline__ float sum8(float4 u, float4 v) {
    return u.x + u.y + u.z + u.w + v.x + v.y + v.z + v.w;
}
__device__ __forceinline__ float sumsq8(float4 u, float4 v) {
    return u.x*u.x + u.y*u.y + u.z*u.z + u.w*u.w
         + v.x*v.x + v.y*v.y + v.z*v.z + v.w*v.w;
}

// sign(x)*|x|^0.7 via hardware exp2/log2
__device__ __forceinline__ float signed_pow07(float raw) {
    float a = fabsf(raw);
    float r = exp2f(0.7f * log2f(fmaxf(a, 1e-38f)));
    return copysignf(r, raw);
}

template <int P, int CHBASE>
__device__ __forceinline__ void spds_scale(const float* __restrict__ x,
                                           float* __restrict__ out,
                                           int tid) {
    constexpr int STRIDE = P / 2;
    constexpr int N = (256 - P) / STRIDE + 1;   // 255 / 127 / 63
    constexpr int NV = (P == 2) ? 7 : 6;
    constexpr int PP = P * P;

    int corner = tid & 3;
    int lane_x = corner & 1;
    int lane_y = corner >> 1;
    int t      = tid >> 2;
    int ox     = t & 31;
    int oy     = (t >> 5) & 31;
    int b      = t >> 10;

    // bilinear source coords, align_corners=False (never clamps for these
    // shapes -> yh==yl+1, xh==xl+1 always; clamps kept as cheap safety)
    const float scale = (float)N / 32.0f;
    float sy = (oy + 0.5f) * scale - 0.5f;
    sy = fminf(fmaxf(sy, 0.0f), (float)(N - 1));
    int   yl = (int)floorf(sy);
    float wy = sy - (float)yl;

    float sx = (ox + 0.5f) * scale - 0.5f;
    sx = fminf(fmaxf(sx, 0.0f), (float)(N - 1));
    int   xl = (int)floorf(sx);
    float wx = sx - (float)xl;

    float w = (lane_y ? wy : 1.0f - wy) * (lane_x ? wx : 1.0f - wx);

    int col0 = (xl + lane_x) * STRIDE;
    const float* xb = x + (size_t)b * 3 * 256 * 256 + col0;

    float vals[7];
    float det = 0.0f;

    #pragma unroll
    for (int c = 0; c < 3; ++c) {
        const float* xc = xb + (size_t)c * 256 * 256;
        float s, ssq, raw = 0.0f;

        if constexpr (P == 8) {
            // union rows [4yl, 4yl+12); this lane loads 6 of them
            int row_base = yl * 4 + (lane_y ? 6 : 0);
            float bs[3] = {0.f, 0.f, 0.f}, bss[3] = {0.f, 0.f, 0.f};
            #pragma unroll
            for (int dy = 0; dy < 6; ++dy) {
                const float4* r = reinterpret_cast<const float4*>(
                    xc + (row_base + dy) * 256);
                float4 u = r[0], v = r[1];
                bs[dy >> 1]  += sum8(u, v);
                bss[dy >> 1] += sumsq8(u, v);
            }
            float alls  = bs[0] + bs[1] + bs[2];
            float allss = bss[0] + bss[1] + bss[2];
            // top patch = rows[0,8): lane0 all 6 rows + lane1 rows{6,7}=bs[0]
            // bot patch = rows[4,12): lane0 rows{4,5}=bs[2] + lane1 all 6
            float tps  = lane_y ? bs[0]  : alls;
            float tpss = lane_y ? bss[0] : allss;
            float bps  = lane_y ? alls   : bs[2];
            float bpss = lane_y ? allss  : bss[2];
            float tts  = tps  + __shfl_xor(tps,  2);
            float ttss = tpss + __shfl_xor(tpss, 2);
            float bts  = bps  + __shfl_xor(bps,  2);
            float btss = bpss + __shfl_xor(bpss, 2);
            s   = lane_y ? bts  : tts;
            ssq = lane_y ? btss : ttss;
        } else if constexpr (P == 4) {
            // union rows [2yl, 2yl+6); this lane loads 3 of them
            int row_base = yl * 2 + (lane_y ? 3 : 0);
            float rs[3], rss[3];
            #pragma unroll
            for (int dy = 0; dy < 3; ++dy) {
                const float2* r = reinterpret_cast<const float2*>(
                    xc + (row_base + dy) * 256);
                float2 u = r[0], v = r[1];
                rs[dy]  = u.x + u.y + v.x + v.y;
                rss[dy] = u.x*u.x + u.y*u.y + v.x*v.x + v.y*v.y;
            }
            float alls  = rs[0] + rs[1] + rs[2];
            float allss = rss[0] + rss[1] + rss[2];
            // top = rows[0,4): lane0 all + lane1 row3=rs[0]
            // bot = rows[2,6): lane0 row2=rs[2] + lane1 all
            float tps  = lane_y ? rs[0]  : alls;
            float tpss = lane_y ? rss[0] : allss;
            float bps  = lane_y ? alls   : rs[2];
            float bpss = lane_y ? allss  : rss[2];
            float tts  = tps  + __shfl_xor(tps,  2);
            float ttss = tpss + __shfl_xor(tpss, 2);
            float bts  = bps  + __shfl_xor(bps,  2);
            float btss = bpss + __shfl_xor(bpss, 2);
            s   = lane_y ? bts  : tts;
            ssq = lane_y ? btss : ttss;
        } else {  // P == 2: each corner loads its own 2x2 (needs raw values)
            int row0 = (yl + lane_y) * 1;
            const float* p0 = xc + row0 * 256;
            float a = p0[0], bb = p0[1], cc = p0[256], d = p0[257];
            s   = a + bb + cc + d;
            ssq = a*a + bb*bb + cc*cc + d*d;
            raw = a * d - bb * cc;
        }

        float mean = s * (1.0f / PP);
        float var  = (ssq - s * s * (1.0f / PP)) * (1.0f / (PP - 1));
        float stdv = sqrtf(fmaxf(var, 0.0f)) + 1e-6f;

        vals[c]     = mean * w;
        vals[3 + c] = stdv * w;
        if constexpr (P == 2) det += signed_pow07(raw);
    }
    if constexpr (P == 2) vals[6] = det * (1.0f / 3.0f) * w;

    // combine the 4 corners (lanes 4k..4k+3)
    #pragma unroll
    for (int i = 0; i < NV; ++i) {
        float v = vals[i];
        v += __shfl_xor(v, 1);
        v += __shfl_xor(v, 2);
        vals[i] = v;
    }

    if (corner == 0) {
        float* ob = out + ((size_t)b * 19 + CHBASE) * 1024 + oy * 32 + ox;
        #pragma unroll
        for (int i = 0; i < NV; ++i)
            ob[(size_t)i * 1024] = vals[i];
    }
}

__global__ __launch_bounds__(256) void spds_fused(const float* __restrict__ x,
                                                  float* __restrict__ out) {
    // XCD swizzle (grid % 8 == 0 guaranteed by launcher): XCD k executes a
    // contiguous chunk of work ids; work ordered 48 blocks per image b
    // (16 P=8 + 16 P=4 + 16 P=2) -> each XCD holds 4 whole images in L2.
    int bid   = blockIdx.x;
    int chunk = gridDim.x >> 3;
    int wid   = (bid & 7) * chunk + (bid >> 3);

    int b    = wid / 48;
    int r    = wid - b * 48;        // 0..47
    int band = r & 15;
    int tid  = (b * 16 + band) * 256 + threadIdx.x;

    if (r < 16) {
        spds_scale<8, 13>(x, out, tid);
    } else if (r < 32) {
        spds_scale<4, 7>(x, out, tid);
    } else {
        spds_scale<2, 0>(x, out, tid);
    }
}

extern "C" void kernel_launch(void* const* d_in, const int* in_sizes, int n_in,
                              void* d_out, int out_size, void* d_ws, size_t ws_size,
                              hipStream_t stream) {
    const float* x   = (const float*)d_in[0];
    float*       out = (float*)d_out;
    int B = in_sizes[0] / (3 * 256 * 256);       // 32
    int grid = B * 48;                           // 48 blocks per image, %8==0
    spds_fused<<<grid, 256, 0, stream>>>(x, out);
}

// Round 4
// 12.537 us; speedup vs baseline: 1.3182x; 1.3182x over previous
//
#include <hip/hip_runtime.h>
#include <math.h>

// Fused SPDS extractor, single dispatch (R3):
//   for p in {2,4,8}: sliding p×p patches (stride p/2) -> per-patch mean,
//   std(ddof=1)+1e-6, and (p==2) channel-mean of sign(det)*|det|^0.7,
//   each plane bilinear-resized (align_corners=False) to 32x32.
//
// Fusion: bilinear downsample reads only the 2x2 neighboring patch positions
// per output pixel -> compute corner-patch stats on the fly and blend.
//
// R3 structure: 2 threads per output pixel (the two y-corners). Each lane
// loads the 12-col (P=8) / 6-col (P=4) / 3-col (P=2) column UNION of the two
// x-corner patches once per row and derives BOTH x-corner sums from it
// (left = q0+q1, right = q1+q2). Both x-patches are complete in-lane: blend
// with bilinear x-weights locally, then one shfl_xor(1) adds the y-pair.
// vs R1: -25% load instrs, -40% VALU, half the shuffles, no divergence.
// (yh==yl+1, xh==xl+1 always for these shapes; clamps kept as cheap safety.)

__device__ __forceinline__ float hsum4(float4 q) { return q.x + q.y + q.z + q.w; }
__device__ __forceinline__ float hsq4(float4 q) {
    return q.x * q.x + q.y * q.y + q.z * q.z + q.w * q.w;
}

// sign(x)*|x|^0.7 via hardware exp2/log2 (abs threshold 5.7e-2 >> error)
__device__ __forceinline__ float signed_pow07(float raw) {
    float a = fabsf(raw);
    float r = exp2f(0.7f * log2f(fmaxf(a, 1e-38f)));   // a==0 -> ~3e-27 ~ 0
    return copysignf(r, raw);
}

template <int P, int CHBASE>
__device__ __forceinline__ void spds_scale(const float* __restrict__ x,
                                           float* __restrict__ out, int tid) {
    constexpr int STRIDE = P / 2;
    constexpr int N = (256 - P) / STRIDE + 1;   // 255 / 127 / 63
    constexpr int NV = (P == 2) ? 7 : 6;
    constexpr int PP = P * P;
    constexpr float INV_PP   = 1.0f / PP;
    constexpr float INV_PPM1 = 1.0f / (PP - 1);

    int lane_y = tid & 1;
    int t      = tid >> 1;
    int ox     = t & 31;
    int oy     = (t >> 5) & 31;
    int b      = t >> 10;

    // bilinear source coords, align_corners=False
    const float scale = (float)N / 32.0f;
    float sy = (oy + 0.5f) * scale - 0.5f;
    sy = fminf(fmaxf(sy, 0.0f), (float)(N - 1));
    int   yl = (int)floorf(sy);
    float wy = sy - (float)yl;

    float sx = (ox + 0.5f) * scale - 0.5f;
    sx = fminf(fmaxf(sx, 0.0f), (float)(N - 1));
    int   xl = (int)floorf(sx);
    float wx = sx - (float)xl;

    float wly = lane_y ? wy : (1.0f - wy);
    float wl  = (1.0f - wx) * wly;   // this y-corner, left x-patch
    float wr  = wx * wly;            // this y-corner, right x-patch

    int row0 = (yl + lane_y) * STRIDE;
    int col0 = xl * STRIDE;          // 4*xl (16B aligned) / 2*xl (8B) / xl
    const float* xb = x + (size_t)b * 3 * 65536 + row0 * 256 + col0;

    float vals[7];
    float det = 0.0f;

    #pragma unroll
    for (int c = 0; c < 3; ++c) {
        const float* xc = xb + (size_t)c * 65536;
        float sl, ssl, sr, ssr;
        float rawl = 0.0f, rawr = 0.0f;

        if constexpr (P == 8) {
            sl = ssl = sr = ssr = 0.0f;
            #pragma unroll
            for (int dy = 0; dy < 8; ++dy) {
                const float4* r = reinterpret_cast<const float4*>(xc + dy * 256);
                float4 q0 = r[0], q1 = r[1], q2 = r[2];
                float s0 = hsum4(q0), s1 = hsum4(q1), s2 = hsum4(q2);
                sl += s0 + s1;  sr += s1 + s2;
                float t0 = hsq4(q0), t1 = hsq4(q1), t2 = hsq4(q2);
                ssl += t0 + t1; ssr += t1 + t2;
            }
        } else if constexpr (P == 4) {
            sl = ssl = sr = ssr = 0.0f;
            #pragma unroll
            for (int dy = 0; dy < 4; ++dy) {
                const float2* r = reinterpret_cast<const float2*>(xc + dy * 256);
                float2 u = r[0], v = r[1], w2 = r[2];
                float s0 = u.x + u.y, s1 = v.x + v.y, s2 = w2.x + w2.y;
                sl += s0 + s1;  sr += s1 + s2;
                float t0 = u.x * u.x + u.y * u.y;
                float t1 = v.x * v.x + v.y * v.y;
                float t2 = w2.x * w2.x + w2.y * w2.y;
                ssl += t0 + t1; ssr += t1 + t2;
            }
        } else {  // P == 2: 2 rows x 3 cols; both 2x2 dets from the 6 values
            float a  = xc[0],   b2 = xc[1],   e = xc[2];
            float c2 = xc[256], d  = xc[257], g = xc[258];
            sl  = a + b2 + c2 + d;
            sr  = b2 + e + d + g;
            ssl = a * a + b2 * b2 + c2 * c2 + d * d;
            ssr = b2 * b2 + e * e + d * d + g * g;
            rawl = a * d - b2 * c2;
            rawr = b2 * g - e * d;
        }

        float ml = sl * INV_PP, mr = sr * INV_PP;
        float vl = (ssl - sl * sl * INV_PP) * INV_PPM1;
        float vr = (ssr - sr * sr * INV_PP) * INV_PPM1;
        float dl = sqrtf(fmaxf(vl, 0.0f)) + 1e-6f;
        float dr = sqrtf(fmaxf(vr, 0.0f)) + 1e-6f;

        vals[c]     = ml * wl + mr * wr;
        vals[3 + c] = dl * wl + dr * wr;
        if constexpr (P == 2)
            det += signed_pow07(rawl) * wl + signed_pow07(rawr) * wr;
    }
    if constexpr (P == 2) vals[6] = det * (1.0f / 3.0f);

    // add the two y-corners (lanes 2k, 2k+1)
    #pragma unroll
    for (int i = 0; i < NV; ++i) {
        float v = vals[i];
        v += __shfl_xor(v, 1);
        vals[i] = v;
    }

    if (lane_y == 0) {
        float* ob = out + ((size_t)b * 19 + CHBASE) * 1024 + oy * 32 + ox;
        #pragma unroll
        for (int i = 0; i < NV; ++i)
            ob[(size_t)i * 1024] = vals[i];
    }
}

__global__ __launch_bounds__(256) void spds_fused(const float* __restrict__ x,
                                                  float* __restrict__ out,
                                                  int blocksPerScale) {
    int bid = blockIdx.x;
    if (bid < blocksPerScale) {
        // heavy scale first
        int tid = bid * 256 + threadIdx.x;
        spds_scale<8, 13>(x, out, tid);
    } else if (bid < 2 * blocksPerScale) {
        int tid = (bid - blocksPerScale) * 256 + threadIdx.x;
        spds_scale<4, 7>(x, out, tid);
    } else {
        int tid = (bid - 2 * blocksPerScale) * 256 + threadIdx.x;
        spds_scale<2, 0>(x, out, tid);
    }
}

extern "C" void kernel_launch(void* const* d_in, const int* in_sizes, int n_in,
                              void* d_out, int out_size, void* d_ws, size_t ws_size,
                              hipStream_t stream) {
    const float* x   = (const float*)d_in[0];
    float*       out = (float*)d_out;
    int B = in_sizes[0] / (3 * 256 * 256);       // 32
    int blocksPerScale = B * 8;                  // B*1024 px * 2 lanes / 256
    spds_fused<<<3 * blocksPerScale, 256, 0, stream>>>(x, out, blocksPerScale);
}

// Round 5
// 11.269 us; speedup vs baseline: 1.4666x; 1.1126x over previous
//
#include <hip/hip_runtime.h>
#include <math.h>

// Fused SPDS extractor, single dispatch (R4):
//   for p in {2,4,8}: sliding p×p patches (stride p/2) -> per-patch mean,
//   std(ddof=1)+1e-6, and (p==2) channel-mean of sign(det)*|det|^0.7,
//   each plane bilinear-resized (align_corners=False) to 32x32.
//
// Structure: 2 threads per output pixel (the two y-corners).
//  * x-union (R3): each lane loads the column union of the two x-corner
//    patches once per row; left = q0+q1, right = q1+q2. Both x-patches
//    complete in-lane -> blend with x-weights locally, one shfl_xor(1) y-add.
//  * y-split (R4, select-free): the lane pair splits the 12-row (P=8) /
//    6-row (P=4) row union evenly. Odd lane iterates its rows in REVERSE so
//    both lanes accumulate X (all rows) and Y (first 4 (resp. 2) iters)
//    with a STATIC unroll. top = X0+(X1-Y1), bottom = X1+(X0-Y0):
//    Z = X-Y, one shfl_xor(1), one add. No cndmask selects (R2's mistake).
//    -25% loads on the dominant scales. (Rows never clamp: max row fits.)

__device__ __forceinline__ float hsum4(float4 q) { return q.x + q.y + q.z + q.w; }
__device__ __forceinline__ float hsq4(float4 q) {
    return q.x * q.x + q.y * q.y + q.z * q.z + q.w * q.w;
}

// sign(x)*|x|^0.7 via hardware exp2/log2 (abs threshold 5.7e-2 >> error)
__device__ __forceinline__ float signed_pow07(float raw) {
    float a = fabsf(raw);
    float r = exp2f(0.7f * log2f(fmaxf(a, 1e-38f)));   // a==0 -> ~3e-27 ~ 0
    return copysignf(r, raw);
}

template <int P, int CHBASE>
__device__ __forceinline__ void spds_scale(const float* __restrict__ x,
                                           float* __restrict__ out, int tid) {
    constexpr int STRIDE = P / 2;
    constexpr int N = (256 - P) / STRIDE + 1;   // 255 / 127 / 63
    constexpr int NV = (P == 2) ? 7 : 6;
    constexpr int PP = P * P;
    constexpr float INV_PP   = 1.0f / PP;
    constexpr float INV_PPM1 = 1.0f / (PP - 1);

    int lane_y = tid & 1;
    int t      = tid >> 1;
    int ox     = t & 31;
    int oy     = (t >> 5) & 31;
    int b      = t >> 10;

    // bilinear source coords, align_corners=False
    const float scale = (float)N / 32.0f;
    float sy = (oy + 0.5f) * scale - 0.5f;
    sy = fminf(fmaxf(sy, 0.0f), (float)(N - 1));
    int   yl = (int)floorf(sy);
    float wy = sy - (float)yl;

    float sx = (ox + 0.5f) * scale - 0.5f;
    sx = fminf(fmaxf(sx, 0.0f), (float)(N - 1));
    int   xl = (int)floorf(sx);
    float wx = sx - (float)xl;

    float wly = lane_y ? wy : (1.0f - wy);
    float wl  = (1.0f - wx) * wly;   // this y-corner, left x-patch
    float wr  = wx * wly;            // this y-corner, right x-patch

    int col0 = xl * STRIDE;          // 4*xl (16B aligned) / 2*xl (8B) / xl
    const float* xb = x + (size_t)b * 3 * 65536 + col0;

    float vals[7];
    float det = 0.0f;

    #pragma unroll
    for (int c = 0; c < 3; ++c) {
        const float* xc = xb + (size_t)c * 65536;
        float sl, ssl, sr, ssr;
        float rawl = 0.0f, rawr = 0.0f;

        if constexpr (P == 8) {
            // row union [4yl, 4yl+12): lane0 rows +0..5 fwd, lane1 +11..6 rev
            int rb    = yl * 4 + (lane_y ? 11 : 0);
            int rstep = lane_y ? -256 : 256;
            const float* p = xc + rb * 256;
            float Xs_l = 0, Xs_r = 0, Xq_l = 0, Xq_r = 0;
            float Ys_l = 0, Ys_r = 0, Yq_l = 0, Yq_r = 0;
            #pragma unroll
            for (int dy = 0; dy < 6; ++dy) {
                const float4* r = reinterpret_cast<const float4*>(p);
                float4 q0 = r[0], q1 = r[1], q2 = r[2];
                float s0 = hsum4(q0), s1 = hsum4(q1), s2 = hsum4(q2);
                float t0 = hsq4(q0),  t1 = hsq4(q1),  t2 = hsq4(q2);
                float srl = s0 + s1, srr = s1 + s2;
                float trl = t0 + t1, trr = t1 + t2;
                Xs_l += srl; Xs_r += srr; Xq_l += trl; Xq_r += trr;
                if (dy < 4) { Ys_l += srl; Ys_r += srr; Yq_l += trl; Yq_r += trr; }
                p += rstep;
            }
            float Zs_l = Xs_l - Ys_l, Zs_r = Xs_r - Ys_r;
            float Zq_l = Xq_l - Yq_l, Zq_r = Xq_r - Yq_r;
            sl  = Xs_l + __shfl_xor(Zs_l, 1);
            sr  = Xs_r + __shfl_xor(Zs_r, 1);
            ssl = Xq_l + __shfl_xor(Zq_l, 1);
            ssr = Xq_r + __shfl_xor(Zq_r, 1);
        } else if constexpr (P == 4) {
            // row union [2yl, 2yl+6): lane0 rows +0..2 fwd, lane1 +5..3 rev
            int rb    = yl * 2 + (lane_y ? 5 : 0);
            int rstep = lane_y ? -256 : 256;
            const float* p = xc + rb * 256;
            float Xs_l = 0, Xs_r = 0, Xq_l = 0, Xq_r = 0;
            float Ys_l = 0, Ys_r = 0, Yq_l = 0, Yq_r = 0;
            #pragma unroll
            for (int dy = 0; dy < 3; ++dy) {
                const float2* r = reinterpret_cast<const float2*>(p);
                float2 u = r[0], v = r[1], w2 = r[2];
                float s0 = u.x + u.y, s1 = v.x + v.y, s2 = w2.x + w2.y;
                float t0 = u.x * u.x + u.y * u.y;
                float t1 = v.x * v.x + v.y * v.y;
                float t2 = w2.x * w2.x + w2.y * w2.y;
                float srl = s0 + s1, srr = s1 + s2;
                float trl = t0 + t1, trr = t1 + t2;
                Xs_l += srl; Xs_r += srr; Xq_l += trl; Xq_r += trr;
                if (dy < 2) { Ys_l += srl; Ys_r += srr; Yq_l += trl; Yq_r += trr; }
                p += rstep;
            }
            float Zs_l = Xs_l - Ys_l, Zs_r = Xs_r - Ys_r;
            float Zq_l = Xq_l - Yq_l, Zq_r = Xq_r - Yq_r;
            sl  = Xs_l + __shfl_xor(Zs_l, 1);
            sr  = Xs_r + __shfl_xor(Zs_r, 1);
            ssl = Xq_l + __shfl_xor(Zq_l, 1);
            ssr = Xq_r + __shfl_xor(Zq_r, 1);
        } else {  // P == 2: 2 rows x 3 cols in-lane; both 2x2 dets need raws
            const float* p0 = xc + (yl + lane_y) * 256;
            float a  = p0[0],   b2 = p0[1],   e = p0[2];
            float c2 = p0[256], d  = p0[257], g = p0[258];
            sl  = a + b2 + c2 + d;
            sr  = b2 + e + d + g;
            ssl = a * a + b2 * b2 + c2 * c2 + d * d;
            ssr = b2 * b2 + e * e + d * d + g * g;
            rawl = a * d - b2 * c2;
            rawr = b2 * g - e * d;
        }

        float ml = sl * INV_PP, mr = sr * INV_PP;
        float vl = (ssl - sl * sl * INV_PP) * INV_PPM1;
        float vr = (ssr - sr * sr * INV_PP) * INV_PPM1;
        float dl = sqrtf(fmaxf(vl, 0.0f)) + 1e-6f;
        float dr = sqrtf(fmaxf(vr, 0.0f)) + 1e-6f;

        vals[c]     = ml * wl + mr * wr;
        vals[3 + c] = dl * wl + dr * wr;
        if constexpr (P == 2)
            det += signed_pow07(rawl) * wl + signed_pow07(rawr) * wr;
    }
    if constexpr (P == 2) vals[6] = det * (1.0f / 3.0f);

    // add the two y-corners (lanes 2k, 2k+1)
    #pragma unroll
    for (int i = 0; i < NV; ++i) {
        float v = vals[i];
        v += __shfl_xor(v, 1);
        vals[i] = v;
    }

    if (lane_y == 0) {
        float* ob = out + ((size_t)b * 19 + CHBASE) * 1024 + oy * 32 + ox;
        #pragma unroll
        for (int i = 0; i < NV; ++i)
            ob[(size_t)i * 1024] = vals[i];
    }
}

__global__ __launch_bounds__(256) void spds_fused(const float* __restrict__ x,
                                                  float* __restrict__ out,
                                                  int blocksPerScale) {
    int bid = blockIdx.x;
    if (bid < blocksPerScale) {
        // heavy scale first
        int tid = bid * 256 + threadIdx.x;
        spds_scale<8, 13>(x, out, tid);
    } else if (bid < 2 * blocksPerScale) {
        int tid = (bid - blocksPerScale) * 256 + threadIdx.x;
        spds_scale<4, 7>(x, out, tid);
    } else {
        int tid = (bid - 2 * blocksPerScale) * 256 + threadIdx.x;
        spds_scale<2, 0>(x, out, tid);
    }
}

extern "C" void kernel_launch(void* const* d_in, const int* in_sizes, int n_in,
                              void* d_out, int out_size, void* d_ws, size_t ws_size,
                              hipStream_t stream) {
    const float* x   = (const float*)d_in[0];
    float*       out = (float*)d_out;
    int B = in_sizes[0] / (3 * 256 * 256);       // 32
    int blocksPerScale = B * 8;                  // B*1024 px * 2 lanes / 256
    spds_fused<<<3 * blocksPerScale, 256, 0, stream>>>(x, out, blocksPerScale);
}

// Round 6
// 11.148 us; speedup vs baseline: 1.4825x; 1.0108x over previous
//
#include <hip/hip_runtime.h>
#include <math.h>

// Fused SPDS extractor, single dispatch (R5):
//   for p in {2,4,8}: sliding p×p patches (stride p/2) -> per-patch mean,
//   std(ddof=1)+1e-6, and (p==2) channel-mean of sign(det)*|det|^0.7,
//   each plane bilinear-resized (align_corners=False) to 32x32.
//
// Structure: 2 threads per output pixel (the two y-corners).
//  * x-union (R3): each lane loads the column union of the two x-corner
//    patches once per row; left = q0+q1, right = q1+q2 — both complete
//    in-lane, blended with x-weights locally, one shfl_xor(1) y-add.
//  * y-split (R4, select-free): lane pair splits the row union evenly;
//    odd lane iterates reversed so X (all rows) and Y (first iters) are
//    statically accumulated; top = X0+(X1-Y1), bot = X1+(X0-Y0) via one
//    shfl_xor(1) on Z=X-Y. No cndmask selects.
//  * channel-split P=8 (R5): one thread per (pixel, y-corner, CHANNEL) for
//    the dominant scale -> 3x more waves at 1/3 the per-thread work; better
//    CU balance and load-latency hiding. Channels write disjoint planes.

__device__ __forceinline__ float hsum4(float4 q) { return q.x + q.y + q.z + q.w; }
__device__ __forceinline__ float hsq4(float4 q) {
    return q.x * q.x + q.y * q.y + q.z * q.z + q.w * q.w;
}

// sign(x)*|x|^0.7 via hardware exp2/log2 (abs threshold 5.7e-2 >> error)
__device__ __forceinline__ float signed_pow07(float raw) {
    float a = fabsf(raw);
    float r = exp2f(0.7f * log2f(fmaxf(a, 1e-38f)));   // a==0 -> ~3e-27 ~ 0
    return copysignf(r, raw);
}

// shared bilinear coord helper
template <int N>
__device__ __forceinline__ void bilin(int o, int& lo, float& w) {
    const float scale = (float)N / 32.0f;
    float s = (o + 0.5f) * scale - 0.5f;
    s = fminf(fmaxf(s, 0.0f), (float)(N - 1));
    lo = (int)floorf(s);
    w = s - (float)lo;
}

// ---- P=8, channel-split: thread = (b, c, oy, ox, lane_y) ----
__device__ __forceinline__ void spds_scale8(const float* __restrict__ x,
                                            float* __restrict__ out, int tid) {
    constexpr int N = 63;
    constexpr float INV_PP = 1.0f / 64.0f, INV_PPM1 = 1.0f / 63.0f;

    int lane_y = tid & 1;
    int t      = tid >> 1;
    int ox     = t & 31;
    int oy     = (t >> 5) & 31;
    int u      = t >> 10;        // 0..3B-1 : (b, c)
    int b      = u / 3;
    int c      = u - 3 * b;

    int yl, xl; float wy, wx;
    bilin<N>(oy, yl, wy);
    bilin<N>(ox, xl, wx);

    float wly = lane_y ? wy : (1.0f - wy);
    float wl  = (1.0f - wx) * wly;
    float wr  = wx * wly;

    const float* xc = x + ((size_t)b * 3 + c) * 65536 + xl * 4;

    // row union [4yl, 4yl+12): lane0 rows +0..5 fwd, lane1 +11..6 rev
    int rb    = yl * 4 + (lane_y ? 11 : 0);
    int rstep = lane_y ? -256 : 256;
    const float* p = xc + rb * 256;
    float Xs_l = 0, Xs_r = 0, Xq_l = 0, Xq_r = 0;
    float Ys_l = 0, Ys_r = 0, Yq_l = 0, Yq_r = 0;
    #pragma unroll
    for (int dy = 0; dy < 6; ++dy) {
        const float4* r = reinterpret_cast<const float4*>(p);
        float4 q0 = r[0], q1 = r[1], q2 = r[2];
        float s0 = hsum4(q0), s1 = hsum4(q1), s2 = hsum4(q2);
        float t0 = hsq4(q0),  t1 = hsq4(q1),  t2 = hsq4(q2);
        float srl = s0 + s1, srr = s1 + s2;
        float trl = t0 + t1, trr = t1 + t2;
        Xs_l += srl; Xs_r += srr; Xq_l += trl; Xq_r += trr;
        if (dy < 4) { Ys_l += srl; Ys_r += srr; Yq_l += trl; Yq_r += trr; }
        p += rstep;
    }
    float Zs_l = Xs_l - Ys_l, Zs_r = Xs_r - Ys_r;
    float Zq_l = Xq_l - Yq_l, Zq_r = Xq_r - Yq_r;
    float sl  = Xs_l + __shfl_xor(Zs_l, 1);
    float sr  = Xs_r + __shfl_xor(Zs_r, 1);
    float ssl = Xq_l + __shfl_xor(Zq_l, 1);
    float ssr = Xq_r + __shfl_xor(Zq_r, 1);

    float ml = sl * INV_PP, mr = sr * INV_PP;
    float vl = (ssl - sl * sl * INV_PP) * INV_PPM1;
    float vr = (ssr - sr * sr * INV_PP) * INV_PPM1;
    float dl = sqrtf(fmaxf(vl, 0.0f)) + 1e-6f;
    float dr = sqrtf(fmaxf(vr, 0.0f)) + 1e-6f;

    float vmean = ml * wl + mr * wr;
    float vstd  = dl * wl + dr * wr;
    vmean += __shfl_xor(vmean, 1);
    vstd  += __shfl_xor(vstd, 1);

    if (lane_y == 0) {
        float* ob = out + ((size_t)b * 19 + 13 + c) * 1024 + oy * 32 + ox;
        ob[0]        = vmean;   // ch 13+c
        ob[3 * 1024] = vstd;    // ch 16+c
    }
}

// ---- P=4 and P=2: thread = (b, oy, ox, lane_y), loops channels ----
template <int P, int CHBASE>
__device__ __forceinline__ void spds_scale(const float* __restrict__ x,
                                           float* __restrict__ out, int tid) {
    constexpr int N = (256 - P) / (P / 2) + 1;   // 127 / 63
    constexpr int NV = (P == 2) ? 7 : 6;
    constexpr int PP = P * P;
    constexpr float INV_PP   = 1.0f / PP;
    constexpr float INV_PPM1 = 1.0f / (PP - 1);

    int lane_y = tid & 1;
    int t      = tid >> 1;
    int ox     = t & 31;
    int oy     = (t >> 5) & 31;
    int b      = t >> 10;

    int yl, xl; float wy, wx;
    bilin<N>(oy, yl, wy);
    bilin<N>(ox, xl, wx);

    float wly = lane_y ? wy : (1.0f - wy);
    float wl  = (1.0f - wx) * wly;
    float wr  = wx * wly;

    const float* xb = x + (size_t)b * 3 * 65536 + xl * (P / 2);

    float vals[7];
    float det = 0.0f;

    #pragma unroll
    for (int c = 0; c < 3; ++c) {
        const float* xc = xb + (size_t)c * 65536;
        float sl, ssl, sr, ssr;
        float rawl = 0.0f, rawr = 0.0f;

        if constexpr (P == 4) {
            // row union [2yl, 2yl+6): lane0 rows +0..2 fwd, lane1 +5..3 rev
            int rb    = yl * 2 + (lane_y ? 5 : 0);
            int rstep = lane_y ? -256 : 256;
            const float* p = xc + rb * 256;
            float Xs_l = 0, Xs_r = 0, Xq_l = 0, Xq_r = 0;
            float Ys_l = 0, Ys_r = 0, Yq_l = 0, Yq_r = 0;
            #pragma unroll
            for (int dy = 0; dy < 3; ++dy) {
                const float2* r = reinterpret_cast<const float2*>(p);
                float2 u = r[0], v = r[1], w2 = r[2];
                float s0 = u.x + u.y, s1 = v.x + v.y, s2 = w2.x + w2.y;
                float t0 = u.x * u.x + u.y * u.y;
                float t1 = v.x * v.x + v.y * v.y;
                float t2 = w2.x * w2.x + w2.y * w2.y;
                float srl = s0 + s1, srr = s1 + s2;
                float trl = t0 + t1, trr = t1 + t2;
                Xs_l += srl; Xs_r += srr; Xq_l += trl; Xq_r += trr;
                if (dy < 2) { Ys_l += srl; Ys_r += srr; Yq_l += trl; Yq_r += trr; }
                p += rstep;
            }
            float Zs_l = Xs_l - Ys_l, Zs_r = Xs_r - Ys_r;
            float Zq_l = Xq_l - Yq_l, Zq_r = Xq_r - Yq_r;
            sl  = Xs_l + __shfl_xor(Zs_l, 1);
            sr  = Xs_r + __shfl_xor(Zs_r, 1);
            ssl = Xq_l + __shfl_xor(Zq_l, 1);
            ssr = Xq_r + __shfl_xor(Zq_r, 1);
        } else {  // P == 2: 2 rows x 3 cols in-lane; both 2x2 dets need raws
            const float* p0 = xc + (yl + lane_y) * 256;
            float a  = p0[0],   b2 = p0[1],   e = p0[2];
            float c2 = p0[256], d  = p0[257], g = p0[258];
            sl  = a + b2 + c2 + d;
            sr  = b2 + e + d + g;
            ssl = a * a + b2 * b2 + c2 * c2 + d * d;
            ssr = b2 * b2 + e * e + d * d + g * g;
            rawl = a * d - b2 * c2;
            rawr = b2 * g - e * d;
        }

        float ml = sl * INV_PP, mr = sr * INV_PP;
        float vl = (ssl - sl * sl * INV_PP) * INV_PPM1;
        float vr = (ssr - sr * sr * INV_PP) * INV_PPM1;
        float dl = sqrtf(fmaxf(vl, 0.0f)) + 1e-6f;
        float dr = sqrtf(fmaxf(vr, 0.0f)) + 1e-6f;

        vals[c]     = ml * wl + mr * wr;
        vals[3 + c] = dl * wl + dr * wr;
        if constexpr (P == 2)
            det += signed_pow07(rawl) * wl + signed_pow07(rawr) * wr;
    }
    if constexpr (P == 2) vals[6] = det * (1.0f / 3.0f);

    // add the two y-corners (lanes 2k, 2k+1)
    #pragma unroll
    for (int i = 0; i < NV; ++i) {
        float v = vals[i];
        v += __shfl_xor(v, 1);
        vals[i] = v;
    }

    if (lane_y == 0) {
        float* ob = out + ((size_t)b * 19 + CHBASE) * 1024 + oy * 32 + ox;
        #pragma unroll
        for (int i = 0; i < NV; ++i)
            ob[(size_t)i * 1024] = vals[i];
    }
}

__global__ __launch_bounds__(256) void spds_fused(const float* __restrict__ x,
                                                  float* __restrict__ out,
                                                  int bps8, int bps) {
    int bid = blockIdx.x;
    if (bid < bps8) {
        // heavy scale first, channel-split
        spds_scale8(x, out, bid * 256 + threadIdx.x);
    } else if (bid < bps8 + bps) {
        spds_scale<4, 7>(x, out, (bid - bps8) * 256 + threadIdx.x);
    } else {
        spds_scale<2, 0>(x, out, (bid - bps8 - bps) * 256 + threadIdx.x);
    }
}

extern "C" void kernel_launch(void* const* d_in, const int* in_sizes, int n_in,
                              void* d_out, int out_size, void* d_ws, size_t ws_size,
                              hipStream_t stream) {
    const float* x   = (const float*)d_in[0];
    float*       out = (float*)d_out;
    int B = in_sizes[0] / (3 * 256 * 256);  // 32
    int bps8 = B * 24;                      // B*3ch*1024px*2 lanes / 256
    int bps  = B * 8;                       // B*1024px*2 lanes / 256
    spds_fused<<<bps8 + 2 * bps, 256, 0, stream>>>(x, out, bps8, bps);
}